// Round 2
// baseline (1902.220 us; speedup 1.0000x reference)
//
#include <hip/hip_runtime.h>

// LayerNorm-LSTM: B=16384, T=16, I=256, H=128, G=4H=512.
// Round 2: split-bf16 (hi+lo) 3-term MFMA for both projections to reach
// ~fp32 precision (the LN-LSTM recurrence amplifies bf16 operand noise ~15x
// over 16 steps -> round-1 absmax 0.266). hi = RTZ(f32>>16), lo = bf16 of
// exact residual; compute hi*hi + lo*hi + hi*lo (dropped lo*lo term ~2^-16).

#define B_  16384
#define T_  16
#define I_  256
#define H_  128
#define G_  512
#define EPS 1e-5f

typedef __attribute__((ext_vector_type(8))) short short8;   // 8 bf16 in 4 VGPRs
typedef __attribute__((ext_vector_type(4))) float f32x4;    // MFMA C/D frag

__device__ __forceinline__ unsigned short f2bf(float f) {
    union { float f; unsigned u; } v; v.f = f;
    unsigned u = v.u;
    return (unsigned short)((u + 0x7FFFu + ((u >> 16) & 1u)) >> 16); // RNE
}
__device__ __forceinline__ float bf2f(unsigned short b) {
    union { unsigned u; float f; } v; v.u = ((unsigned)b) << 16;
    return v.f;
}
// split f32 -> hi (RTZ bf16) + lo (bf16 of exact residual)
__device__ __forceinline__ void split_bf(float x, unsigned short& hi, unsigned short& lo) {
    union { float f; unsigned u; } v; v.f = x;
    hi = (unsigned short)(v.u >> 16);
    lo = f2bf(x - bf2f(hi));
}

__device__ __forceinline__ float sigm_(float x) { return 1.0f / (1.0f + __expf(-x)); }
__device__ __forceinline__ float tanh_(float x) { return 1.0f - 2.0f / (__expf(2.0f * x) + 1.0f); }

// LDS gate buffer index with quad-XOR swizzle (2-way bank aliasing max = free).
#define GIDX(g, row, col) ((((g) * 32 + (row)) * 128) + ((col) ^ (((row) & 12) << 2)))

__global__ void prep_kernel(const float* __restrict__ Wih, const float* __restrict__ Whh,
                            const float* __restrict__ h0,  const float* __restrict__ c0,
                            unsigned short* __restrict__ wih_hi, unsigned short* __restrict__ wih_lo,
                            unsigned short* __restrict__ whh_hi, unsigned short* __restrict__ whh_lo,
                            unsigned short* __restrict__ h_hi,   unsigned short* __restrict__ h_lo,
                            float* __restrict__ c_ws) {
    const int NW_IH = G_ * I_;          // 131072
    const int NW_HH = G_ * H_;          // 65536
    const int NBH   = B_ * H_;          // 2097152
    const int NTOT  = NW_IH + NW_HH + NBH + NBH;
    int stride = gridDim.x * blockDim.x;
    for (int i = blockIdx.x * blockDim.x + threadIdx.x; i < NTOT; i += stride) {
        int j = i;
        unsigned short hi, lo;
        if (j < NW_IH) { split_bf(Wih[j], hi, lo); wih_hi[j] = hi; wih_lo[j] = lo; continue; }
        j -= NW_IH;
        if (j < NW_HH) { split_bf(Whh[j], hi, lo); whh_hi[j] = hi; whh_lo[j] = lo; continue; }
        j -= NW_HH;
        if (j < NBH)   { split_bf(h0[j], hi, lo); h_hi[j] = hi; h_lo[j] = lo; continue; }
        j -= NBH;
        c_ws[j] = c0[j];
    }
}

__launch_bounds__(256)
__global__ void step_kernel(const float* __restrict__ x,               // [B,T,I] fp32
                            const unsigned short* __restrict__ wih_hi, // [G,I] bf16 hi
                            const unsigned short* __restrict__ wih_lo, // [G,I] bf16 lo
                            const unsigned short* __restrict__ whh_hi, // [G,H] bf16 hi
                            const unsigned short* __restrict__ whh_lo, // [G,H] bf16 lo
                            unsigned short* __restrict__ h_hi,         // [B,H] bf16 (in/out)
                            unsigned short* __restrict__ h_lo,         // [B,H] bf16 (in/out)
                            float* __restrict__ c_ws,                  // [B,H] fp32 (in/out)
                            const float* __restrict__ gx, const float* __restrict__ bx,
                            const float* __restrict__ gh, const float* __restrict__ bh,
                            const float* __restrict__ bias,
                            const float* __restrict__ gc, const float* __restrict__ bc,
                            float* __restrict__ out, int t) {
    __shared__ float gates[4 * 32 * 128];   // 64 KB: [gate][row 0..31][col 0..127] (swizzled)

    const int tid  = threadIdx.x;
    const int w    = tid >> 6;     // wave id == gate chunk id (0:i 1:f 2:g 3:o)
    const int lane = tid & 63;
    const int l15  = lane & 15;
    const int quad = lane >> 4;
    const int b0   = blockIdx.x * 32;

    // Per-column constants for this wave's gate chunk (col = w*128 + c*16 + l15)
    float gx_c[8], gh_c[8], bs_c[8];
#pragma unroll
    for (int c = 0; c < 8; ++c) {
        int col = w * 128 + c * 16 + l15;
        gx_c[c] = gx[col];
        gh_c[c] = gh[col];
        bs_c[c] = bx[col] + bh[col] + bias[col];
    }

    f32x4 acc[2][8];

    // ---------- Phase A: x @ W_ih^T (K=256), split-bf16 3-term MFMA ----------
#pragma unroll
    for (int r = 0; r < 2; ++r)
#pragma unroll
        for (int c = 0; c < 8; ++c) acc[r][c] = (f32x4){0.f, 0.f, 0.f, 0.f};

    for (int kk = 0; kk < 8; ++kk) {
        int k0 = kk * 32 + quad * 8;
        short8 ahi[2], alo[2];
#pragma unroll
        for (int r = 0; r < 2; ++r) {
            int row = b0 + r * 16 + l15;
            const float* xp = x + ((size_t)row * T_ + t) * I_ + k0;
            float4 v0 = *(const float4*)xp;
            float4 v1 = *(const float4*)(xp + 4);
            float v[8] = {v0.x, v0.y, v0.z, v0.w, v1.x, v1.y, v1.z, v1.w};
            short8 h8, l8;
#pragma unroll
            for (int j = 0; j < 8; ++j) {
                unsigned short hb, lb;
                split_bf(v[j], hb, lb);
                h8[j] = (short)hb; l8[j] = (short)lb;
            }
            ahi[r] = h8; alo[r] = l8;
        }
#pragma unroll
        for (int c = 0; c < 8; ++c) {
            size_t off = (size_t)(w * 128 + c * 16 + l15) * I_ + k0;
            short8 bhi = *(const short8*)(wih_hi + off);
            short8 blo = *(const short8*)(wih_lo + off);
#pragma unroll
            for (int r = 0; r < 2; ++r) {
                acc[r][c] = __builtin_amdgcn_mfma_f32_16x16x32_bf16(ahi[r], bhi, acc[r][c], 0, 0, 0);
                acc[r][c] = __builtin_amdgcn_mfma_f32_16x16x32_bf16(alo[r], bhi, acc[r][c], 0, 0, 0);
                acc[r][c] = __builtin_amdgcn_mfma_f32_16x16x32_bf16(ahi[r], blo, acc[r][c], 0, 0, 0);
            }
        }
    }

    // Per-row LN across the 128 cols of this gate chunk.
    // C-layout: value i of tile (r,c) sits at row r*16+quad*4+i, col c*16+l15.
#pragma unroll
    for (int r = 0; r < 2; ++r) {
        float s[4] = {0.f, 0.f, 0.f, 0.f}, ss[4] = {0.f, 0.f, 0.f, 0.f};
#pragma unroll
        for (int c = 0; c < 8; ++c)
#pragma unroll
            for (int i = 0; i < 4; ++i) {
                float v = acc[r][c][i];
                s[i] += v; ss[i] += v * v;
            }
#pragma unroll
        for (int m = 1; m < 16; m <<= 1)
#pragma unroll
            for (int i = 0; i < 4; ++i) {
                s[i]  += __shfl_xor(s[i],  m);
                ss[i] += __shfl_xor(ss[i], m);
            }
#pragma unroll
        for (int i = 0; i < 4; ++i) {
            float mu  = s[i] * (1.0f / 128.0f);
            float var = ss[i] * (1.0f / 128.0f) - mu * mu;
            float rs  = rsqrtf(var + EPS);
            int row = r * 16 + quad * 4 + i;
#pragma unroll
            for (int c = 0; c < 8; ++c) {
                float zn = (acc[r][c][i] - mu) * rs;
                gates[GIDX(w, row, c * 16 + l15)] = zn * gx_c[c] + bs_c[c];
            }
        }
    }

    // ---------- Phase B: h @ W_hh^T (K=128), split-bf16 3-term MFMA ----------
#pragma unroll
    for (int r = 0; r < 2; ++r)
#pragma unroll
        for (int c = 0; c < 8; ++c) acc[r][c] = (f32x4){0.f, 0.f, 0.f, 0.f};

    for (int kk = 0; kk < 4; ++kk) {
        int k0 = kk * 32 + quad * 8;
        short8 ahi[2], alo[2];
#pragma unroll
        for (int r = 0; r < 2; ++r) {
            int row = b0 + r * 16 + l15;
            ahi[r] = *(const short8*)(h_hi + (size_t)row * H_ + k0);
            alo[r] = *(const short8*)(h_lo + (size_t)row * H_ + k0);
        }
#pragma unroll
        for (int c = 0; c < 8; ++c) {
            size_t off = (size_t)(w * 128 + c * 16 + l15) * H_ + k0;
            short8 bhi = *(const short8*)(whh_hi + off);
            short8 blo = *(const short8*)(whh_lo + off);
#pragma unroll
            for (int r = 0; r < 2; ++r) {
                acc[r][c] = __builtin_amdgcn_mfma_f32_16x16x32_bf16(ahi[r], bhi, acc[r][c], 0, 0, 0);
                acc[r][c] = __builtin_amdgcn_mfma_f32_16x16x32_bf16(alo[r], bhi, acc[r][c], 0, 0, 0);
                acc[r][c] = __builtin_amdgcn_mfma_f32_16x16x32_bf16(ahi[r], blo, acc[r][c], 0, 0, 0);
            }
        }
    }

#pragma unroll
    for (int r = 0; r < 2; ++r) {
        float s[4] = {0.f, 0.f, 0.f, 0.f}, ss[4] = {0.f, 0.f, 0.f, 0.f};
#pragma unroll
        for (int c = 0; c < 8; ++c)
#pragma unroll
            for (int i = 0; i < 4; ++i) {
                float v = acc[r][c][i];
                s[i] += v; ss[i] += v * v;
            }
#pragma unroll
        for (int m = 1; m < 16; m <<= 1)
#pragma unroll
            for (int i = 0; i < 4; ++i) {
                s[i]  += __shfl_xor(s[i],  m);
                ss[i] += __shfl_xor(ss[i], m);
            }
#pragma unroll
        for (int i = 0; i < 4; ++i) {
            float mu  = s[i] * (1.0f / 128.0f);
            float var = ss[i] * (1.0f / 128.0f) - mu * mu;
            float rs  = rsqrtf(var + EPS);
            int row = r * 16 + quad * 4 + i;
#pragma unroll
            for (int c = 0; c < 8; ++c) {
                float hn = (acc[r][c][i] - mu) * rs;
                int gi = GIDX(w, row, c * 16 + l15);
                gates[gi] += hn * gh_c[c];   // same lane wrote this addr in phase A
            }
        }
    }

    __syncthreads();

    // ---------- Phase 2: cell update + cell-LN + outputs ----------
    // Wave w handles rows w*8 .. w*8+7; per row, 64 lanes x 2 cols cover H=128.
    float gcv0 = gc[lane], gcv1 = gc[lane + 64];
    float bcv0 = bc[lane], bcv1 = bc[lane + 64];

    for (int rr = 0; rr < 8; ++rr) {
        int row = w * 8 + rr;
        int b   = b0 + row;
        float cn0, cn1, og0, og1;
        float s = 0.f, ss = 0.f;
        {
            int col = lane;
            float iv = gates[GIDX(0, row, col)];
            float fv = gates[GIDX(1, row, col)];
            float gv = gates[GIDX(2, row, col)];
            og0      = gates[GIDX(3, row, col)];
            float cp = c_ws[(size_t)b * H_ + col];
            cn0 = sigm_(fv) * cp + sigm_(iv) * tanh_(gv);
            s += cn0; ss += cn0 * cn0;
        }
        {
            int col = lane + 64;
            float iv = gates[GIDX(0, row, col)];
            float fv = gates[GIDX(1, row, col)];
            float gv = gates[GIDX(2, row, col)];
            og1      = gates[GIDX(3, row, col)];
            float cp = c_ws[(size_t)b * H_ + col];
            cn1 = sigm_(fv) * cp + sigm_(iv) * tanh_(gv);
            s += cn1; ss += cn1 * cn1;
        }
#pragma unroll
        for (int m = 1; m < 64; m <<= 1) {
            s  += __shfl_xor(s,  m);
            ss += __shfl_xor(ss, m);
        }
        float mu  = s * (1.0f / 128.0f);
        float var = ss * (1.0f / 128.0f) - mu * mu;
        float rs  = rsqrtf(var + EPS);

        {
            int col = lane;
            float cln = (cn0 - mu) * rs * gcv0 + bcv0;
            float h   = sigm_(og0) * tanh_(cln);
            unsigned short hb, lb; split_bf(h, hb, lb);
            c_ws[(size_t)b * H_ + col] = cn0;
            h_hi[(size_t)b * H_ + col] = hb;
            h_lo[(size_t)b * H_ + col] = lb;
            out[((size_t)b * T_ + t) * H_ + col] = h;
            if (t == T_ - 1) out[(size_t)B_ * T_ * H_ + (size_t)b * H_ + col] = h;
        }
        {
            int col = lane + 64;
            float cln = (cn1 - mu) * rs * gcv1 + bcv1;
            float h   = sigm_(og1) * tanh_(cln);
            unsigned short hb, lb; split_bf(h, hb, lb);
            c_ws[(size_t)b * H_ + col] = cn1;
            h_hi[(size_t)b * H_ + col] = hb;
            h_lo[(size_t)b * H_ + col] = lb;
            out[((size_t)b * T_ + t) * H_ + col] = h;
            if (t == T_ - 1) out[(size_t)B_ * T_ * H_ + (size_t)b * H_ + col] = h;
        }
    }
}

extern "C" void kernel_launch(void* const* d_in, const int* in_sizes, int n_in,
                              void* d_out, int out_size, void* d_ws, size_t ws_size,
                              hipStream_t stream) {
    const float* x    = (const float*)d_in[0];
    const float* h0   = (const float*)d_in[1];
    const float* c0   = (const float*)d_in[2];
    const float* Wih  = (const float*)d_in[3];
    const float* Whh  = (const float*)d_in[4];
    const float* bias = (const float*)d_in[5];
    const float* gx   = (const float*)d_in[6];
    const float* bx   = (const float*)d_in[7];
    const float* gh   = (const float*)d_in[8];
    const float* bh   = (const float*)d_in[9];
    const float* gc   = (const float*)d_in[10];
    const float* bc   = (const float*)d_in[11];
    float* out = (float*)d_out;

    // ws layout (~17 MB): Wih hi/lo | Whh hi/lo | h hi/lo | c fp32
    char* ws = (char*)d_ws;
    size_t o = 0;
    unsigned short* wih_hi = (unsigned short*)(ws + o); o += (size_t)G_ * I_ * 2;   // 256 KB
    unsigned short* wih_lo = (unsigned short*)(ws + o); o += (size_t)G_ * I_ * 2;   // 256 KB
    unsigned short* whh_hi = (unsigned short*)(ws + o); o += (size_t)G_ * H_ * 2;   // 128 KB
    unsigned short* whh_lo = (unsigned short*)(ws + o); o += (size_t)G_ * H_ * 2;   // 128 KB
    unsigned short* h_hi   = (unsigned short*)(ws + o); o += (size_t)B_ * H_ * 2;   // 4 MB
    unsigned short* h_lo   = (unsigned short*)(ws + o); o += (size_t)B_ * H_ * 2;   // 4 MB
    float*          c_ws   = (float*)(ws + o);                                      // 8 MB

    hipLaunchKernelGGL(prep_kernel, dim3(2048), dim3(256), 0, stream,
                       Wih, Whh, h0, c0, wih_hi, wih_lo, whh_hi, whh_lo, h_hi, h_lo, c_ws);

    for (int t = 0; t < T_; ++t) {
        hipLaunchKernelGGL(step_kernel, dim3(B_ / 32), dim3(256), 0, stream,
                           x, wih_hi, wih_lo, whh_hi, whh_lo, h_hi, h_lo, c_ws,
                           gx, bx, gh, bh, bias, gc, bc, out, t);
    }
}